// Round 11
// baseline (216.926 us; speedup 1.0000x reference)
//
#include <hip/hip_runtime.h>
#include <stdint.h>

#define B_DIM 4
#define T_DIM 2048
#define C_DIM 1024
#define H_DIM 16
#define D_DIM 64
#define M_DIM (B_DIM * T_DIM)   // 8192
// 1/sqrt(D) * log2(e): QK^T lands in exp2 domain
#define QK_SCALE 0.18033688011112042f

typedef float f32x4 __attribute__((ext_vector_type(4)));
typedef float f32x16 __attribute__((ext_vector_type(16)));
typedef short bf16x8 __attribute__((ext_vector_type(8)));
typedef unsigned short u16;
typedef u16 u16x8 __attribute__((ext_vector_type(8)));

static __device__ __forceinline__ u16 f2b(float f) {
  uint32_t r;
  asm("v_cvt_pk_bf16_f32 %0, %1, %1" : "=v"(r) : "v"(f));
  return (u16)r;
}
static __device__ __forceinline__ uint32_t f2b2(float a, float b) {
  uint32_t r;
  asm("v_cvt_pk_bf16_f32 %0, %1, %2" : "=v"(r) : "v"(a), "v"(b));
  return r;
}
static __device__ __forceinline__ float xhalf_max(float x) {
  return fmaxf(x, __shfl_xor(x, 32, 64));
}
static __device__ __forceinline__ float xhalf_sum(float x) {
  return x + __shfl_xor(x, 32, 64);
}

static __device__ __forceinline__ void gl_lds16(const u16* g, u16* l) {
  __builtin_amdgcn_global_load_lds(
      (const __attribute__((address_space(1))) void*)g,
      (__attribute__((address_space(3))) void*)l, 16, 0, 0);
}

// ---------------- fused f32 -> bf16 convert (x + 4 weights, one dispatch) ----
__global__ void k_cvt_all(const float* __restrict__ x,
                          const float* __restrict__ s0, const float* __restrict__ s1,
                          const float* __restrict__ s2, const float* __restrict__ s3,
                          u16* __restrict__ dx,
                          u16* __restrict__ d0, u16* __restrict__ d1,
                          u16* __restrict__ d2, u16* __restrict__ d3) {
  int i = blockIdx.x * blockDim.x + threadIdx.x;
  const float* s;
  u16* d;
  int j;
  if (i < (1 << 21)) {
    s = x; d = dx; j = i;
  } else {
    int k = i - (1 << 21);
    int seg = k >> 18;
    j = k & ((1 << 18) - 1);
    s = seg == 0 ? s0 : seg == 1 ? s1 : seg == 2 ? s2 : s3;
    d = seg == 0 ? d0 : seg == 1 ? d1 : seg == 2 ? d2 : d3;
  }
  float4 v = ((const float4*)s)[j];
  uint2 o;
  o.x = f2b2(v.x, v.y);
  o.y = f2b2(v.z, v.w);
  ((uint2*)d)[j] = o;
}

// ---------------- fused QKV GEMM (proven 128x128 2-phase structure) ----------
__global__ __launch_bounds__(256) void k_gemm_qkv(
    const u16* __restrict__ A,
    const u16* __restrict__ w0, const u16* __restrict__ w1, const u16* __restrict__ w2,
    const float* __restrict__ b0, const float* __restrict__ b1, const float* __restrict__ b2,
    u16* __restrict__ Qo, u16* __restrict__ Ko, u16* __restrict__ Vto) {
  __shared__ u16 As[128 * 32];
  __shared__ u16 Bs[128 * 32];
  const int tid = threadIdx.x;
  const int l = tid & 63;
  const int w = tid >> 6;
  const int wr = w >> 1, wc = w & 1;
  const int seg = blockIdx.x >> 3;
  const int brow = blockIdx.y * 128, bcol = (blockIdx.x & 7) * 128;
  const int lrow = l & 15, lk = l >> 4;
  const int K = C_DIM;

  const u16* Bw = seg == 0 ? w0 : seg == 1 ? w1 : w2;
  const float* bias = seg == 0 ? b0 : seg == 1 ? b1 : b2;
  const float scale = seg == 0 ? QK_SCALE : 1.f;

  f32x4 acc[4][4];
  for (int m = 0; m < 4; ++m)
    for (int n = 0; n < 4; ++n)
      acc[m][n] = (f32x4){0.f, 0.f, 0.f, 0.f};

  for (int kt = 0; kt < K; kt += 32) {
    __syncthreads();
    {
      int slot = tid;
      int r0 = slot >> 2, c0 = slot & 3;
      gl_lds16(A + (size_t)(brow + r0) * K + kt + c0 * 8, As + slot * 8);
      gl_lds16(Bw + (size_t)(bcol + r0) * K + kt + c0 * 8, Bs + slot * 8);
      int slot2 = slot + 256;
      int r1 = slot2 >> 2, c1 = slot2 & 3;
      gl_lds16(A + (size_t)(brow + r1) * K + kt + c1 * 8, As + slot2 * 8);
      gl_lds16(Bw + (size_t)(bcol + r1) * K + kt + c1 * 8, Bs + slot2 * 8);
    }
    asm volatile("s_waitcnt vmcnt(0)" ::: "memory");
    __syncthreads();

    bf16x8 af[4], bfr[4];
#pragma unroll
    for (int m = 0; m < 4; ++m)
      af[m] = *(const bf16x8*)(As + (wr * 64 + m * 16 + lrow) * 32 + lk * 8);
#pragma unroll
    for (int n = 0; n < 4; ++n)
      bfr[n] = *(const bf16x8*)(Bs + (wc * 64 + n * 16 + lrow) * 32 + lk * 8);
#pragma unroll
    for (int m = 0; m < 4; ++m) {
#pragma unroll
      for (int n = 0; n < 4; ++n)
        acc[m][n] = __builtin_amdgcn_mfma_f32_16x16x32_bf16(af[m], bfr[n], acc[m][n], 0, 0, 0);
    }
  }

#pragma unroll
  for (int m = 0; m < 4; ++m) {
    int rg0 = brow + wr * 64 + m * 16 + lk * 4;
    int bb = rg0 >> 11, tt0 = rg0 & (T_DIM - 1);
#pragma unroll
    for (int n = 0; n < 4; ++n) {
      int cg = bcol + wc * 64 + n * 16 + lrow;
      float bv = bias[cg];
      int hh = cg >> 6, dd = cg & 63;
      if (seg == 2) {
        float v0 = acc[m][n][0] + bv, v1 = acc[m][n][1] + bv;
        float v2 = acc[m][n][2] + bv, v3 = acc[m][n][3] + bv;
        uint2 pv;
        pv.x = f2b2(v0, v1);
        pv.y = f2b2(v2, v3);
        *(uint2*)(Vto + (((size_t)bb * H_DIM + hh) * D_DIM + dd) * T_DIM + tt0) = pv;
      } else {
        u16* Out = seg == 0 ? Qo : Ko;
#pragma unroll
        for (int i = 0; i < 4; ++i) {
          float val = (acc[m][n][i] + bv) * scale;
          Out[(((size_t)bb * H_DIM + hh) * T_DIM + tt0 + i) * D_DIM + dd] = f2b(val);
        }
      }
    }
  }
}

// ---------------- output projection GEMM: out = A @ W^T + b (f32 out) --------
__global__ __launch_bounds__(256) void k_gemm_proj(
    const u16* __restrict__ A, const u16* __restrict__ Bw,
    const float* __restrict__ bias, float* __restrict__ Cout) {
  __shared__ u16 As[128 * 32];
  __shared__ u16 Bs[128 * 32];
  const int tid = threadIdx.x;
  const int l = tid & 63;
  const int w = tid >> 6;
  const int wr = w >> 1, wc = w & 1;
  const int brow = blockIdx.y * 128, bcol = blockIdx.x * 128;
  const int lrow = l & 15, lk = l >> 4;
  const int K = C_DIM, N = C_DIM;

  f32x4 acc[4][4];
  for (int m = 0; m < 4; ++m)
    for (int n = 0; n < 4; ++n)
      acc[m][n] = (f32x4){0.f, 0.f, 0.f, 0.f};

  for (int kt = 0; kt < K; kt += 32) {
    __syncthreads();
    {
      int slot = tid;
      int r0 = slot >> 2, c0 = slot & 3;
      gl_lds16(A + (size_t)(brow + r0) * K + kt + c0 * 8, As + slot * 8);
      gl_lds16(Bw + (size_t)(bcol + r0) * K + kt + c0 * 8, Bs + slot * 8);
      int slot2 = slot + 256;
      int r1 = slot2 >> 2, c1 = slot2 & 3;
      gl_lds16(A + (size_t)(brow + r1) * K + kt + c1 * 8, As + slot2 * 8);
      gl_lds16(Bw + (size_t)(bcol + r1) * K + kt + c1 * 8, Bs + slot2 * 8);
    }
    asm volatile("s_waitcnt vmcnt(0)" ::: "memory");
    __syncthreads();

    bf16x8 af[4], bfr[4];
#pragma unroll
    for (int m = 0; m < 4; ++m)
      af[m] = *(const bf16x8*)(As + (wr * 64 + m * 16 + lrow) * 32 + lk * 8);
#pragma unroll
    for (int n = 0; n < 4; ++n)
      bfr[n] = *(const bf16x8*)(Bs + (wc * 64 + n * 16 + lrow) * 32 + lk * 8);
#pragma unroll
    for (int m = 0; m < 4; ++m) {
#pragma unroll
      for (int n = 0; n < 4; ++n)
        acc[m][n] = __builtin_amdgcn_mfma_f32_16x16x32_bf16(af[m], bfr[n], acc[m][n], 0, 0, 0);
    }
  }

#pragma unroll
  for (int m = 0; m < 4; ++m) {
    int rg0 = brow + wr * 64 + m * 16 + lk * 4;
#pragma unroll
    for (int n = 0; n < 4; ++n) {
      int cg = bcol + wc * 64 + n * 16 + lrow;
      float bv = bias[cg];
#pragma unroll
      for (int i = 0; i < 4; ++i)
        Cout[(size_t)(rg0 + i) * N + cg] = acc[m][n][i] + bv;
    }
  }
}

// ---------------- causal flash attention: 8 waves x 32 q-rows, KVBLK=128 -----
// XCD-aware balanced grid: id = xcd + 8*slot + 64*j (+256 for light half);
// bh = xcd*8+slot (all blocks of a head on ONE XCD's L2), qb = half? j : 7-j
// (CU c gets qb pair {7-j, j} -> equal work on every CU).
// Joint-128 softmax: one mask/max/exp2/sum chain per 128 kv (halved chains).
__global__ __launch_bounds__(512) void k_attn(
    const u16* __restrict__ Q, const u16* __restrict__ Kg,
    const u16* __restrict__ Vt, u16* __restrict__ O) {
  __shared__ u16 Ks[2][128 * 64];   // [kv 128][d 64], XOR-swizzled
  __shared__ u16 Vs[2][64 * 128];   // [d 64][kv 128], XOR-swizzled

  const int tid = threadIdx.x;
  const int l = tid & 63;
  const int w = tid >> 6;
  const int id = blockIdx.x;
  const int xcd = id & 7;
  const int half = id >> 8;                 // 0 = heavy, 1 = light
  const int idh = id & 255;
  const int slot = (idh >> 3) & 7;
  const int j = idh >> 6;                   // 0..3
  const int bh = xcd * 8 + slot;
  const int qb = half ? j : 7 - j;
  const int q0 = qb * 256;
  const int ql = l & 31;
  const int hi = l >> 5;
  const int r0 = q0 + w * 32;
  const int qg = r0 + ql;

  const size_t qkbase = (size_t)bh * T_DIM * D_DIM;
  const size_t vtbase = (size_t)bh * D_DIM * T_DIM;

  const int sr = tid >> 3, sc = tid & 7;
  const int kcol = (sc ^ (sr & 7)) * 8;
  const int vr = tid >> 4, vc = tid & 15;
  const int vcol = (vc ^ (vr & 7)) * 8;

#define STAGE(buf, kt)                                                                    \
  {                                                                                       \
    gl_lds16(Kg + qkbase + (size_t)((kt) * 128 + sr) * D_DIM + kcol, Ks[buf] + tid * 8);  \
    gl_lds16(Kg + qkbase + (size_t)((kt) * 128 + 64 + sr) * D_DIM + kcol,                 \
             Ks[buf] + 4096 + tid * 8);                                                   \
    gl_lds16(Vt + vtbase + (size_t)vr * T_DIM + (kt) * 128 + vcol, Vs[buf] + tid * 8);    \
    gl_lds16(Vt + vtbase + (size_t)(vr + 32) * T_DIM + (kt) * 128 + vcol,                 \
             Vs[buf] + 4096 + tid * 8);                                                   \
  }

  bf16x8 qf[4];
#pragma unroll
  for (int kk = 0; kk < 4; ++kk)
    qf[kk] = *(const bf16x8*)(Q + qkbase + (size_t)qg * D_DIM + kk * 16 + hi * 8);

  f32x16 oacc[2];
#pragma unroll
  for (int dt = 0; dt < 2; ++dt)
#pragma unroll
    for (int r = 0; r < 16; ++r) oacc[dt][r] = 0.f;
  float m_run = -1e30f, l_run = 0.f;

  const int tdx = r0 >> 7;                  // wave's last needed 128-tile
  const int nkt = (q0 >> 7) + 2;

  STAGE(0, 0);

  for (int kt = 0; kt < nkt; ++kt) {
    const int cur = kt & 1;
    if (kt + 1 < nkt) {
      STAGE(cur ^ 1, kt + 1);
      asm volatile("s_waitcnt vmcnt(4)" ::: "memory");
    } else {
      asm volatile("s_waitcnt vmcnt(0)" ::: "memory");
    }
    __syncthreads();

    if (kt <= tdx) {
      // ---- S^T for all 128 kv: s4[a] covers kv = kt*128 + a*32 + crow(r,hi) ----
      f32x16 s4[4];
#pragma unroll
      for (int a = 0; a < 4; ++a)
#pragma unroll
        for (int r = 0; r < 16; ++r) s4[a][r] = 0.f;

      __builtin_amdgcn_s_setprio(1);
#pragma unroll
      for (int h2 = 0; h2 < 2; ++h2) {
        const u16* Kt = Ks[cur] + h2 * 4096;
#pragma unroll
        for (int kk = 0; kk < 4; ++kk) {
#pragma unroll
          for (int aa = 0; aa < 2; ++aa) {
            int row = aa * 32 + ql;
            int blk = (kk * 2 + hi) ^ (row & 7);
            bf16x8 kf = *(const bf16x8*)(Kt + row * 64 + blk * 8);
            s4[h2 * 2 + aa] =
                __builtin_amdgcn_mfma_f32_32x32x16_bf16(kf, qf[kk], s4[h2 * 2 + aa], 0, 0, 0);
          }
        }
      }
      __builtin_amdgcn_s_setprio(0);

      // ---- causal mask (only the wave's diagonal 128-tile) ----
      if (kt == tdx) {
#pragma unroll
        for (int a = 0; a < 4; ++a) {
#pragma unroll
          for (int r = 0; r < 16; ++r) {
            int kv = kt * 128 + a * 32 + (r & 3) + 8 * (r >> 2) + 4 * hi;
            if (kv > qg) s4[a][r] = -1e30f;
          }
        }
      }

      // ---- joint row max over 128 kv ----
      float t16[16];
#pragma unroll
      for (int r = 0; r < 16; ++r)
        t16[r] = fmaxf(fmaxf(s4[0][r], s4[1][r]), fmaxf(s4[2][r], s4[3][r]));
#pragma unroll
      for (int r = 0; r < 8; ++r) t16[r] = fmaxf(t16[r], t16[r + 8]);
#pragma unroll
      for (int r = 0; r < 4; ++r) t16[r] = fmaxf(t16[r], t16[r + 4]);
      float pm = fmaxf(fmaxf(t16[0], t16[1]), fmaxf(t16[2], t16[3]));
      pm = xhalf_max(pm);

      // ---- defer-max (THR=8, exp2 domain) ----
      if (__any(pm > m_run + 8.f)) {
        float mn = fmaxf(m_run, pm);
        float sc_ = exp2f(m_run - mn);
        m_run = mn;
        l_run *= sc_;
#pragma unroll
        for (int dt = 0; dt < 2; ++dt)
#pragma unroll
          for (int r = 0; r < 16; ++r) oacc[dt][r] *= sc_;
      }

      // ---- P = exp2(S - m), joint row sum ----
      float rs0 = 0.f, rs1 = 0.f, rs2 = 0.f, rs3 = 0.f;
#pragma unroll
      for (int a = 0; a < 4; ++a) {
#pragma unroll
        for (int r = 0; r < 16; ++r) {
          float p = exp2f(s4[a][r] - m_run);
          s4[a][r] = p;
          if ((r & 3) == 0) rs0 += p;
          else if ((r & 3) == 1) rs1 += p;
          else if ((r & 3) == 2) rs2 += p;
          else rs3 += p;
        }
      }
      float rs = (rs0 + rs1) + (rs2 + rs3);
      l_run += xhalf_sum(rs);

      // ---- PV over both halves ----
#pragma unroll
      for (int h2 = 0; h2 < 2; ++h2) {
#pragma unroll
        for (int kk = 0; kk < 4; ++kk) {
          const int a = h2 * 2 + (kk >> 1);
          const int base = (kk & 1) * 8;
          union { uint32_t wd[4]; bf16x8 v; } pf;
#pragma unroll
          for (int i = 0; i < 2; ++i) {
            uint32_t Aw = f2b2(s4[a][base + 2 * i], s4[a][base + 2 * i + 1]);
            uint32_t Bw = f2b2(s4[a][base + 4 + 2 * i], s4[a][base + 5 + 2 * i]);
            uint32_t As_ = (uint32_t)__shfl_xor((int)Aw, 32, 64);
            uint32_t Bs_ = (uint32_t)__shfl_xor((int)Bw, 32, 64);
            pf.wd[i] = hi ? Bs_ : Aw;
            pf.wd[2 + i] = hi ? Bw : As_;
          }
          __builtin_amdgcn_s_setprio(1);
#pragma unroll
          for (int dt = 0; dt < 2; ++dt) {
            int row = dt * 32 + ql;
            int chunk = (h2 * 8) + ((kk * 2 + hi) ^ (row & 7));
            bf16x8 vf = *(const bf16x8*)(Vs[cur] + row * 128 + chunk * 8);
            oacc[dt] = __builtin_amdgcn_mfma_f32_32x32x16_bf16(vf, pf.v, oacc[dt], 0, 0, 0);
          }
          __builtin_amdgcn_s_setprio(0);
        }
      }
    }
    __syncthreads();
  }

  const int bb = bh >> 4, hh = bh & 15;
  const float inv = 1.f / l_run;
  u16* orow = O + ((size_t)bb * T_DIM + qg) * C_DIM + hh * D_DIM;
#pragma unroll
  for (int dt = 0; dt < 2; ++dt) {
#pragma unroll
    for (int g = 0; g < 4; ++g) {
      uint2 val;
      val.x = f2b2(oacc[dt][g * 4 + 0] * inv, oacc[dt][g * 4 + 1] * inv);
      val.y = f2b2(oacc[dt][g * 4 + 2] * inv, oacc[dt][g * 4 + 3] * inv);
      *(uint2*)(orow + dt * 32 + g * 8 + 4 * hi) = val;
    }
  }
}

// ---------------- host launcher ----------------
extern "C" void kernel_launch(void* const* d_in, const int* in_sizes, int n_in,
                              void* d_out, int out_size, void* d_ws, size_t ws_size,
                              hipStream_t stream) {
  (void)in_sizes; (void)n_in; (void)out_size; (void)ws_size;
  const float* x  = (const float*)d_in[0];
  const float* wq = (const float*)d_in[1];
  const float* bq = (const float*)d_in[2];
  const float* wk = (const float*)d_in[3];
  const float* bk = (const float*)d_in[4];
  const float* wv = (const float*)d_in[5];
  const float* bv = (const float*)d_in[6];
  const float* wo = (const float*)d_in[7];
  const float* bo = (const float*)d_in[8];
  float* out = (float*)d_out;

  u16* xb  = (u16*)d_ws;
  u16* wqb = xb + (size_t)M_DIM * C_DIM;
  u16* wkb = wqb + (size_t)C_DIM * C_DIM;
  u16* wvb = wkb + (size_t)C_DIM * C_DIM;
  u16* wob = wvb + (size_t)C_DIM * C_DIM;
  u16* Qb  = wob + (size_t)C_DIM * C_DIM;
  u16* Kb  = Qb + (size_t)M_DIM * C_DIM;
  u16* Vtb = Kb + (size_t)M_DIM * C_DIM;
  u16* Ob  = Vtb + (size_t)M_DIM * C_DIM;

  k_cvt_all<<<12288, 256, 0, stream>>>(x, wq, wk, wv, wo, xb, wqb, wkb, wvb, wob);

  k_gemm_qkv<<<dim3(24, M_DIM / 128), 256, 0, stream>>>(
      xb, wqb, wkb, wvb, bq, bk, bv, Qb, Kb, Vtb);

  k_attn<<<512, 512, 0, stream>>>(Qb, Kb, Vtb, Ob);
  k_gemm_proj<<<dim3(C_DIM / 128, M_DIM / 128), 256, 0, stream>>>(Ob, wob, bo, out);
}

// Round 12
// 194.027 us; speedup vs baseline: 1.1180x; 1.1180x over previous
//
#include <hip/hip_runtime.h>
#include <stdint.h>

#define B_DIM 4
#define T_DIM 2048
#define C_DIM 1024
#define H_DIM 16
#define D_DIM 64
#define M_DIM (B_DIM * T_DIM)   // 8192
// 1/sqrt(D) * log2(e): QK^T lands in exp2 domain
#define QK_SCALE 0.18033688011112042f

typedef float f32x4 __attribute__((ext_vector_type(4)));
typedef float f32x16 __attribute__((ext_vector_type(16)));
typedef short bf16x8 __attribute__((ext_vector_type(8)));
typedef unsigned short u16;
typedef u16 u16x8 __attribute__((ext_vector_type(8)));

static __device__ __forceinline__ u16 f2b(float f) {
  uint32_t r;
  asm("v_cvt_pk_bf16_f32 %0, %1, %1" : "=v"(r) : "v"(f));
  return (u16)r;
}
static __device__ __forceinline__ uint32_t f2b2(float a, float b) {
  uint32_t r;
  asm("v_cvt_pk_bf16_f32 %0, %1, %2" : "=v"(r) : "v"(a), "v"(b));
  return r;
}
static __device__ __forceinline__ float xhalf_max(float x) {
  return fmaxf(x, __shfl_xor(x, 32, 64));
}
static __device__ __forceinline__ float xhalf_sum(float x) {
  return x + __shfl_xor(x, 32, 64);
}

static __device__ __forceinline__ void gl_lds16(const u16* g, u16* l) {
  __builtin_amdgcn_global_load_lds(
      (const __attribute__((address_space(1))) void*)g,
      (__attribute__((address_space(3))) void*)l, 16, 0, 0);
}

// ---------------- fused f32 -> bf16 convert (x + 4 weights, one dispatch) ----
__global__ void k_cvt_all(const float* __restrict__ x,
                          const float* __restrict__ s0, const float* __restrict__ s1,
                          const float* __restrict__ s2, const float* __restrict__ s3,
                          u16* __restrict__ dx,
                          u16* __restrict__ d0, u16* __restrict__ d1,
                          u16* __restrict__ d2, u16* __restrict__ d3) {
  int i = blockIdx.x * blockDim.x + threadIdx.x;
  const float* s;
  u16* d;
  int j;
  if (i < (1 << 21)) {
    s = x; d = dx; j = i;
  } else {
    int k = i - (1 << 21);
    int seg = k >> 18;
    j = k & ((1 << 18) - 1);
    s = seg == 0 ? s0 : seg == 1 ? s1 : seg == 2 ? s2 : s3;
    d = seg == 0 ? d0 : seg == 1 ? d1 : seg == 2 ? d2 : d3;
  }
  float4 v = ((const float4*)s)[j];
  uint2 o;
  o.x = f2b2(v.x, v.y);
  o.y = f2b2(v.z, v.w);
  ((uint2*)d)[j] = o;
}

// ---------------- fused QKV GEMM (proven 128x128 2-phase structure) ----------
__global__ __launch_bounds__(256) void k_gemm_qkv(
    const u16* __restrict__ A,
    const u16* __restrict__ w0, const u16* __restrict__ w1, const u16* __restrict__ w2,
    const float* __restrict__ b0, const float* __restrict__ b1, const float* __restrict__ b2,
    u16* __restrict__ Qo, u16* __restrict__ Ko, u16* __restrict__ Vto) {
  __shared__ u16 As[128 * 32];
  __shared__ u16 Bs[128 * 32];
  const int tid = threadIdx.x;
  const int l = tid & 63;
  const int w = tid >> 6;
  const int wr = w >> 1, wc = w & 1;
  const int seg = blockIdx.x >> 3;
  const int brow = blockIdx.y * 128, bcol = (blockIdx.x & 7) * 128;
  const int lrow = l & 15, lk = l >> 4;
  const int K = C_DIM;

  const u16* Bw = seg == 0 ? w0 : seg == 1 ? w1 : w2;
  const float* bias = seg == 0 ? b0 : seg == 1 ? b1 : b2;
  const float scale = seg == 0 ? QK_SCALE : 1.f;

  f32x4 acc[4][4];
  for (int m = 0; m < 4; ++m)
    for (int n = 0; n < 4; ++n)
      acc[m][n] = (f32x4){0.f, 0.f, 0.f, 0.f};

  for (int kt = 0; kt < K; kt += 32) {
    __syncthreads();
    {
      int slot = tid;
      int r0 = slot >> 2, c0 = slot & 3;
      gl_lds16(A + (size_t)(brow + r0) * K + kt + c0 * 8, As + slot * 8);
      gl_lds16(Bw + (size_t)(bcol + r0) * K + kt + c0 * 8, Bs + slot * 8);
      int slot2 = slot + 256;
      int r1 = slot2 >> 2, c1 = slot2 & 3;
      gl_lds16(A + (size_t)(brow + r1) * K + kt + c1 * 8, As + slot2 * 8);
      gl_lds16(Bw + (size_t)(bcol + r1) * K + kt + c1 * 8, Bs + slot2 * 8);
    }
    asm volatile("s_waitcnt vmcnt(0)" ::: "memory");
    __syncthreads();

    bf16x8 af[4], bfr[4];
#pragma unroll
    for (int m = 0; m < 4; ++m)
      af[m] = *(const bf16x8*)(As + (wr * 64 + m * 16 + lrow) * 32 + lk * 8);
#pragma unroll
    for (int n = 0; n < 4; ++n)
      bfr[n] = *(const bf16x8*)(Bs + (wc * 64 + n * 16 + lrow) * 32 + lk * 8);
#pragma unroll
    for (int m = 0; m < 4; ++m) {
#pragma unroll
      for (int n = 0; n < 4; ++n)
        acc[m][n] = __builtin_amdgcn_mfma_f32_16x16x32_bf16(af[m], bfr[n], acc[m][n], 0, 0, 0);
    }
  }

#pragma unroll
  for (int m = 0; m < 4; ++m) {
    int rg0 = brow + wr * 64 + m * 16 + lk * 4;
    int bb = rg0 >> 11, tt0 = rg0 & (T_DIM - 1);
#pragma unroll
    for (int n = 0; n < 4; ++n) {
      int cg = bcol + wc * 64 + n * 16 + lrow;
      float bv = bias[cg];
      int hh = cg >> 6, dd = cg & 63;
      if (seg == 2) {
        float v0 = acc[m][n][0] + bv, v1 = acc[m][n][1] + bv;
        float v2 = acc[m][n][2] + bv, v3 = acc[m][n][3] + bv;
        uint2 pv;
        pv.x = f2b2(v0, v1);
        pv.y = f2b2(v2, v3);
        *(uint2*)(Vto + (((size_t)bb * H_DIM + hh) * D_DIM + dd) * T_DIM + tt0) = pv;
      } else {
        u16* Out = seg == 0 ? Qo : Ko;
#pragma unroll
        for (int i = 0; i < 4; ++i) {
          float val = (acc[m][n][i] + bv) * scale;
          Out[(((size_t)bb * H_DIM + hh) * T_DIM + tt0 + i) * D_DIM + dd] = f2b(val);
        }
      }
    }
  }
}

// ---------------- output projection GEMM: out = A @ W^T + b (f32 out) --------
__global__ __launch_bounds__(256) void k_gemm_proj(
    const u16* __restrict__ A, const u16* __restrict__ Bw,
    const float* __restrict__ bias, float* __restrict__ Cout) {
  __shared__ u16 As[128 * 32];
  __shared__ u16 Bs[128 * 32];
  const int tid = threadIdx.x;
  const int l = tid & 63;
  const int w = tid >> 6;
  const int wr = w >> 1, wc = w & 1;
  const int brow = blockIdx.y * 128, bcol = blockIdx.x * 128;
  const int lrow = l & 15, lk = l >> 4;
  const int K = C_DIM, N = C_DIM;

  f32x4 acc[4][4];
  for (int m = 0; m < 4; ++m)
    for (int n = 0; n < 4; ++n)
      acc[m][n] = (f32x4){0.f, 0.f, 0.f, 0.f};

  for (int kt = 0; kt < K; kt += 32) {
    __syncthreads();
    {
      int slot = tid;
      int r0 = slot >> 2, c0 = slot & 3;
      gl_lds16(A + (size_t)(brow + r0) * K + kt + c0 * 8, As + slot * 8);
      gl_lds16(Bw + (size_t)(bcol + r0) * K + kt + c0 * 8, Bs + slot * 8);
      int slot2 = slot + 256;
      int r1 = slot2 >> 2, c1 = slot2 & 3;
      gl_lds16(A + (size_t)(brow + r1) * K + kt + c1 * 8, As + slot2 * 8);
      gl_lds16(Bw + (size_t)(bcol + r1) * K + kt + c1 * 8, Bs + slot2 * 8);
    }
    asm volatile("s_waitcnt vmcnt(0)" ::: "memory");
    __syncthreads();

    bf16x8 af[4], bfr[4];
#pragma unroll
    for (int m = 0; m < 4; ++m)
      af[m] = *(const bf16x8*)(As + (wr * 64 + m * 16 + lrow) * 32 + lk * 8);
#pragma unroll
    for (int n = 0; n < 4; ++n)
      bfr[n] = *(const bf16x8*)(Bs + (wc * 64 + n * 16 + lrow) * 32 + lk * 8);
#pragma unroll
    for (int m = 0; m < 4; ++m) {
#pragma unroll
      for (int n = 0; n < 4; ++n)
        acc[m][n] = __builtin_amdgcn_mfma_f32_16x16x32_bf16(af[m], bfr[n], acc[m][n], 0, 0, 0);
    }
  }

#pragma unroll
  for (int m = 0; m < 4; ++m) {
    int rg0 = brow + wr * 64 + m * 16 + lk * 4;
#pragma unroll
    for (int n = 0; n < 4; ++n) {
      int cg = bcol + wc * 64 + n * 16 + lrow;
      float bv = bias[cg];
#pragma unroll
      for (int i = 0; i < 4; ++i)
        Cout[(size_t)(rg0 + i) * N + cg] = acc[m][n][i] + bv;
    }
  }
}

// ---------------- causal flash attention: 8 waves x 32 q-rows, KVBLK=128 -----
// XCD-aware balanced grid (r11, kept): bh = xcd*8+slot pins each head to one
// XCD's L2; CU pair {7-j, j} balances work. Softmax: r10-proven two-subtile
// form (64 VGPR, no spill).
__global__ __launch_bounds__(512) void k_attn(
    const u16* __restrict__ Q, const u16* __restrict__ Kg,
    const u16* __restrict__ Vt, u16* __restrict__ O) {
  __shared__ u16 Ks[2][128 * 64];   // [kv 128][d 64], XOR-swizzled
  __shared__ u16 Vs[2][64 * 128];   // [d 64][kv 128], XOR-swizzled

  const int tid = threadIdx.x;
  const int l = tid & 63;
  const int w = tid >> 6;
  const int id = blockIdx.x;
  const int xcd = id & 7;
  const int half = id >> 8;                 // 0 = heavy, 1 = light
  const int idh = id & 255;
  const int slot = (idh >> 3) & 7;
  const int j = idh >> 6;                   // 0..3
  const int bh = xcd * 8 + slot;
  const int qb = half ? j : 7 - j;
  const int q0 = qb * 256;
  const int ql = l & 31;
  const int hi = l >> 5;
  const int r0 = q0 + w * 32;
  const int qg = r0 + ql;

  const size_t qkbase = (size_t)bh * T_DIM * D_DIM;
  const size_t vtbase = (size_t)bh * D_DIM * T_DIM;

  const int sr = tid >> 3, sc = tid & 7;
  const int kcol = (sc ^ (sr & 7)) * 8;
  const int vr = tid >> 4, vc = tid & 15;
  const int vcol = (vc ^ (vr & 7)) * 8;

#define STAGE(buf, kt)                                                                    \
  {                                                                                       \
    gl_lds16(Kg + qkbase + (size_t)((kt) * 128 + sr) * D_DIM + kcol, Ks[buf] + tid * 8);  \
    gl_lds16(Kg + qkbase + (size_t)((kt) * 128 + 64 + sr) * D_DIM + kcol,                 \
             Ks[buf] + 4096 + tid * 8);                                                   \
    gl_lds16(Vt + vtbase + (size_t)vr * T_DIM + (kt) * 128 + vcol, Vs[buf] + tid * 8);    \
    gl_lds16(Vt + vtbase + (size_t)(vr + 32) * T_DIM + (kt) * 128 + vcol,                 \
             Vs[buf] + 4096 + tid * 8);                                                   \
  }

  bf16x8 qf[4];
#pragma unroll
  for (int kk = 0; kk < 4; ++kk)
    qf[kk] = *(const bf16x8*)(Q + qkbase + (size_t)qg * D_DIM + kk * 16 + hi * 8);

  f32x16 oacc[2];
#pragma unroll
  for (int dt = 0; dt < 2; ++dt)
#pragma unroll
    for (int r = 0; r < 16; ++r) oacc[dt][r] = 0.f;
  float m_run = -1e30f, l_run = 0.f;

  const int tdiag64 = r0 >> 6;             // wave's diagonal 64-kv sub-tile
  const int nkt = (q0 >> 7) + 2;           // 128-kv tiles per block

  STAGE(0, 0);

  for (int kt = 0; kt < nkt; ++kt) {
    const int cur = kt & 1;
    if (kt + 1 < nkt) {
      STAGE(cur ^ 1, kt + 1);
      asm volatile("s_waitcnt vmcnt(4)" ::: "memory");
    } else {
      asm volatile("s_waitcnt vmcnt(0)" ::: "memory");
    }
    __syncthreads();

#pragma unroll
    for (int h2 = 0; h2 < 2; ++h2) {
      const int kt64 = kt * 2 + h2;
      if (kt64 <= tdiag64) {
        const u16* Kt = Ks[cur] + h2 * 4096;
        f32x16 s[2];
#pragma unroll
        for (int a = 0; a < 2; ++a)
#pragma unroll
          for (int r = 0; r < 16; ++r) s[a][r] = 0.f;

        __builtin_amdgcn_s_setprio(1);
#pragma unroll
        for (int kk = 0; kk < 4; ++kk) {
#pragma unroll
          for (int a = 0; a < 2; ++a) {
            int row = a * 32 + ql;
            int blk = (kk * 2 + hi) ^ (row & 7);
            bf16x8 kf = *(const bf16x8*)(Kt + row * 64 + blk * 8);
            s[a] = __builtin_amdgcn_mfma_f32_32x32x16_bf16(kf, qf[kk], s[a], 0, 0, 0);
          }
        }
        __builtin_amdgcn_s_setprio(0);

        if (kt64 == tdiag64) {
#pragma unroll
          for (int a = 0; a < 2; ++a) {
#pragma unroll
            for (int r = 0; r < 16; ++r) {
              int kv = kt64 * 64 + a * 32 + (r & 3) + 8 * (r >> 2) + 4 * hi;
              if (kv > qg) s[a][r] = -1e30f;
            }
          }
        }

        float t[16];
#pragma unroll
        for (int r = 0; r < 16; ++r) t[r] = fmaxf(s[0][r], s[1][r]);
#pragma unroll
        for (int r = 0; r < 8; ++r) t[r] = fmaxf(t[r], t[r + 8]);
#pragma unroll
        for (int r = 0; r < 4; ++r) t[r] = fmaxf(t[r], t[r + 4]);
        float pm = fmaxf(fmaxf(t[0], t[1]), fmaxf(t[2], t[3]));
        pm = xhalf_max(pm);

        if (__any(pm > m_run + 8.f)) {
          float mn = fmaxf(m_run, pm);
          float sc_ = exp2f(m_run - mn);
          m_run = mn;
          l_run *= sc_;
#pragma unroll
          for (int dt = 0; dt < 2; ++dt)
#pragma unroll
            for (int r = 0; r < 16; ++r) oacc[dt][r] *= sc_;
        }

        float rs0 = 0.f, rs1 = 0.f, rs2 = 0.f, rs3 = 0.f;
#pragma unroll
        for (int a = 0; a < 2; ++a) {
#pragma unroll
          for (int r = 0; r < 16; ++r) {
            float p = exp2f(s[a][r] - m_run);
            s[a][r] = p;
            if ((r & 3) == 0) rs0 += p;
            else if ((r & 3) == 1) rs1 += p;
            else if ((r & 3) == 2) rs2 += p;
            else rs3 += p;
          }
        }
        float rs = (rs0 + rs1) + (rs2 + rs3);
        l_run += xhalf_sum(rs);

#pragma unroll
        for (int kk = 0; kk < 4; ++kk) {
          const int a = kk >> 1;
          const int base = (kk & 1) * 8;
          union { uint32_t wd[4]; bf16x8 v; } pf;
#pragma unroll
          for (int i = 0; i < 2; ++i) {
            uint32_t Aw = f2b2(s[a][base + 2 * i], s[a][base + 2 * i + 1]);
            uint32_t Bw = f2b2(s[a][base + 4 + 2 * i], s[a][base + 5 + 2 * i]);
            uint32_t As_ = (uint32_t)__shfl_xor((int)Aw, 32, 64);
            uint32_t Bs_ = (uint32_t)__shfl_xor((int)Bw, 32, 64);
            pf.wd[i] = hi ? Bs_ : Aw;
            pf.wd[2 + i] = hi ? Bw : As_;
          }
          __builtin_amdgcn_s_setprio(1);
#pragma unroll
          for (int dt = 0; dt < 2; ++dt) {
            int row = dt * 32 + ql;
            int chunk = (h2 * 8) + ((kk * 2 + hi) ^ (row & 7));
            bf16x8 vf = *(const bf16x8*)(Vs[cur] + row * 128 + chunk * 8);
            oacc[dt] = __builtin_amdgcn_mfma_f32_32x32x16_bf16(vf, pf.v, oacc[dt], 0, 0, 0);
          }
          __builtin_amdgcn_s_setprio(0);
        }
      }
    }
    __syncthreads();
  }

  const int bb = bh >> 4, hh = bh & 15;
  const float inv = 1.f / l_run;
  u16* orow = O + ((size_t)bb * T_DIM + qg) * C_DIM + hh * D_DIM;
#pragma unroll
  for (int dt = 0; dt < 2; ++dt) {
#pragma unroll
    for (int g = 0; g < 4; ++g) {
      uint2 val;
      val.x = f2b2(oacc[dt][g * 4 + 0] * inv, oacc[dt][g * 4 + 1] * inv);
      val.y = f2b2(oacc[dt][g * 4 + 2] * inv, oacc[dt][g * 4 + 3] * inv);
      *(uint2*)(orow + dt * 32 + g * 8 + 4 * hi) = val;
    }
  }
}

// ---------------- host launcher ----------------
extern "C" void kernel_launch(void* const* d_in, const int* in_sizes, int n_in,
                              void* d_out, int out_size, void* d_ws, size_t ws_size,
                              hipStream_t stream) {
  (void)in_sizes; (void)n_in; (void)out_size; (void)ws_size;
  const float* x  = (const float*)d_in[0];
  const float* wq = (const float*)d_in[1];
  const float* bq = (const float*)d_in[2];
  const float* wk = (const float*)d_in[3];
  const float* bk = (const float*)d_in[4];
  const float* wv = (const float*)d_in[5];
  const float* bv = (const float*)d_in[6];
  const float* wo = (const float*)d_in[7];
  const float* bo = (const float*)d_in[8];
  float* out = (float*)d_out;

  u16* xb  = (u16*)d_ws;
  u16* wqb = xb + (size_t)M_DIM * C_DIM;
  u16* wkb = wqb + (size_t)C_DIM * C_DIM;
  u16* wvb = wkb + (size_t)C_DIM * C_DIM;
  u16* wob = wvb + (size_t)C_DIM * C_DIM;
  u16* Qb  = wob + (size_t)C_DIM * C_DIM;
  u16* Kb  = Qb + (size_t)M_DIM * C_DIM;
  u16* Vtb = Kb + (size_t)M_DIM * C_DIM;
  u16* Ob  = Vtb + (size_t)M_DIM * C_DIM;

  k_cvt_all<<<12288, 256, 0, stream>>>(x, wq, wk, wv, wo, xb, wqb, wkb, wvb, wob);

  k_gemm_qkv<<<dim3(24, M_DIM / 128), 256, 0, stream>>>(
      xb, wqb, wkb, wvb, bq, bk, bv, Qb, Kb, Vtb);

  k_attn<<<512, 512, 0, stream>>>(Qb, Kb, Vtb, Ob);
  k_gemm_proj<<<dim3(C_DIM / 128, M_DIM / 128), 256, 0, stream>>>(Ob, wob, bo, out);
}